// Round 5
// baseline (316.361 us; speedup 1.0000x reference)
//
#include <hip/hip_runtime.h>
#include <stdint.h>

#define NB 8
#define F_IN 6300
#define NT 500
#define HID 32
#define NOUT 20
#define NW 99   // u64 mask words per (b,t) row: ceil(6300/64)
#define NWD 8   // u64 words per (b,f) packed time row: ceil(500/64)

// float32 constants, rounded exactly as np.float32 would round the doubles
#define D_SR   0.7788007830714049f     // exp(-1/4)
#define S_SR   0.6795704571147613f     // e/4
#define D_REF  0.36787944117144233f    // exp(-1)
#define C_REF  -5.43656365691809f      // -2*e

#define NROWB ((NB * F_IN) / 4)        // 12600 pack blocks (4 rows each)

// ---------------- K0: pack x into time-bitmasks (binary input!) + transpose w1 ----------------
__global__ __launch_bounds__(256) void k0_pack(const float* __restrict__ x,
                                               const float* __restrict__ w1,
                                               uint64_t* __restrict__ xb,
                                               float* __restrict__ w1t) {
  const int bid = blockIdx.x;
  const int tid = threadIdx.x;
  if (bid < NROWB) {
    const int row = bid * 4 + (tid >> 6);      // row = b*F_IN + f
    const int lane = tid & 63;
    const float* xr = x + (size_t)row * NT;
    uint64_t m[8];
#pragma unroll
    for (int k = 0; k < 8; k++) {
      int t = k * 64 + lane;
      float v = (t < NT) ? xr[t] : 0.f;
      m[k] = __ballot(v > 0.5f);
    }
    if (lane == 0) {
      uint64_t* dst = xb + (size_t)row * NWD;
#pragma unroll
      for (int k = 0; k < 8; k++) dst[k] = m[k];
    }
    return;
  }
  // ---- transpose w1 [32][6300] -> w1t [6300][32] ----
  __shared__ float tl[64][33];
  const int f0 = (bid - NROWB) * 64;
  const int r = tid & 63, g = tid >> 6;
#pragma unroll
  for (int oo = 0; oo < 32; oo += 4) {
    int o = oo + g;
    int f = f0 + r;
    tl[r][o] = (f < F_IN) ? w1[o * F_IN + f] : 0.f;
  }
  __syncthreads();
#pragma unroll
  for (int k = 0; k < 8; k++) {
    int idx = k * 256 + tid;
    int rr = idx >> 5, cc = idx & 31;
    int f = f0 + rr;
    if (f < F_IN) w1t[(size_t)f * 32 + cc] = tl[rr][cc];
  }
}

// ---------------- K1: layer 1 (psp -> spike) from packed bits, exact-order f32 ----------------
__global__ __launch_bounds__(64, 1) void k1_layer1(const uint64_t* __restrict__ xb,
                                                   uint64_t* __restrict__ masks) {
  const int wi = blockIdx.x;
  const int b  = blockIdx.y;
  const int lane = threadIdx.x;
  const int f = wi * 64 + lane;
  const uint64_t vmask = __ballot(f < F_IN);
  const int fc = (f < F_IN) ? f : (F_IN - 1);
  const uint64_t* xr = xb + ((size_t)b * F_IN + fc) * NWD;
  uint64_t* mrow = masks + ((size_t)b * NW + wi) * NT;

  float y1 = 0.f, z1 = 0.f, yr = 0.f, zr = 0.f;
  uint64_t wcur = xr[0];

#pragma unroll 1
  for (int gg = 0; gg < 8; gg++) {
    const int gn = (gg < 7) ? gg + 1 : 7;
    uint64_t wnxt = xr[gn];
    const uint32_t wlo = (uint32_t)wcur;
    const uint32_t whi = (uint32_t)(wcur >> 32);
    uint64_t keep = 0;
#pragma unroll
    for (int j = 0; j < 64; j++) {
      const uint32_t bw = (j < 32) ? wlo : whi;
      const bool xbit = ((bw >> (j & 31)) & 1u) != 0u;
      float zm = __fmul_rn(D_SR, z1);
      y1 = __fmul_rn(D_SR, __fadd_rn(y1, z1));
      z1 = xbit ? __fadd_rn(zm, 1.0f) : zm;
      float p = __fmul_rn(S_SR, y1);
      yr = __fmul_rn(D_REF, __fadd_rn(yr, zr));
      float u = __fadd_rn(p, __fmul_rn(C_REF, yr));
      bool s = (u >= 1.0f);
      float zrm = __fmul_rn(D_REF, zr);
      zr = s ? __fadd_rn(zrm, 1.0f) : zrm;
      uint64_t mball = __ballot(s);
      if (lane == j) keep = mball;
    }
    uint64_t* mp = mrow + gg * 64;
    if (gg < 7)                 mp[lane] = keep & vmask;
    else if (lane < NT - 7*64)  mp[lane] = keep & vmask;
    wcur = wnxt;
  }
}

// ---------------- K2: sparse fc1: R[b,t,o] = sum_{f active} w1t[f][o] (f64) ----------------
__global__ __launch_bounds__(512) void k2_fc1(const float* __restrict__ w1t,
                                              const uint64_t* __restrict__ masks,
                                              double* __restrict__ R) {
  __shared__ double part[8][32];
  const int tid = threadIdx.x;
  const int wv = tid >> 6;
  const int lane = tid & 63;
  const int half = lane >> 5;
  const int o = lane & 31;
  const int b = blockIdx.x;
  const int t = blockIdx.y * 4 + (wv & 3);
  const int seg = wv >> 2;
  const int wbeg = seg * 50, wend = seg ? NW : 50;
  const uint64_t* mbase = masks + (size_t)b * NW * NT + t;
  const char* wrow = (const char*)w1t + o * 4;
  double acc0 = 0.0, acc1 = 0.0, acc2 = 0.0, acc3 = 0.0;

  int wi = wbeg + half;
  uint64_t mcur = (wi < wend) ? mbase[(size_t)wi * NT] : 0;
  for (; wi < wend; wi += 2) {
    uint64_t mnext = (wi + 2 < wend) ? mbase[(size_t)(wi + 2) * NT] : 0;
    const uint32_t base0 = ((uint32_t)wi << 13);
    uint32_t w = (uint32_t)mcur;
    uint32_t boff = base0;
#pragma unroll
    for (int sub = 0; sub < 2; sub++) {
      while (w) {
        uint32_t i0 = __builtin_ctz(w);                 uint32_t w1_ = w & (w - 1);
        uint32_t i1 = w1_ ? __builtin_ctz(w1_) : 0u;    uint32_t w2_ = w1_ ? (w1_ & (w1_ - 1)) : 0u;
        uint32_t i2 = w2_ ? __builtin_ctz(w2_) : 0u;    uint32_t w3_ = w2_ ? (w2_ & (w2_ - 1)) : 0u;
        uint32_t i3 = w3_ ? __builtin_ctz(w3_) : 0u;    w = w3_ ? (w3_ & (w3_ - 1)) : 0u;
        float a0 = *(const float*)(wrow + boff + (i0 << 7));
        float a1 = *(const float*)(wrow + boff + (i1 << 7));
        float a2 = *(const float*)(wrow + boff + (i2 << 7));
        float a3 = *(const float*)(wrow + boff + (i3 << 7));
        a1 = w1_ ? a1 : 0.0f;
        a2 = w2_ ? a2 : 0.0f;
        a3 = w3_ ? a3 : 0.0f;
        acc0 += (double)a0;
        acc1 += (double)a1;
        acc2 += (double)a2;
        acc3 += (double)a3;
      }
      w = (uint32_t)(mcur >> 32);
      boff = base0 + (32u << 7);
    }
    mcur = mnext;
  }
  double acc = (acc0 + acc1) + (acc2 + acc3);
  int hi2 = __shfl_xor(__double2hiint(acc), 32);
  int lo2 = __shfl_xor(__double2loint(acc), 32);
  acc += __hiloint2double(hi2, lo2);
  if (half == 0) part[wv][o] = acc;
  __syncthreads();
  if (wv < 4 && half == 0) {
    double tot = part[wv][o] + part[wv + 4][o];
    R[((size_t)b * NT + t) * HID + o] = tot;   // [b][t][o]: coalesced 256-B store
  }
}

// ---- refractory-only f64 step: verbatim tail of the verified fast-step, p precomputed ----
#define REF_STEP(pin, EMIT)                                                     \
  {                                                                             \
    double u0 = __builtin_fma(cr, q, (pin));                                    \
    double u1 = u0 + K;                                                         \
    double u  = sp ? u1 : u0;                                                   \
    bool s = (u >= 1.0);                                                        \
    double yr = q + (sp ? dre : 0.0);                                           \
    double zr = zrd + (sp ? 1.0 : 0.0);                                         \
    zrd = dre * zr;                                                             \
    q = __builtin_fma(dre, yr, dre * zrd);                                      \
    sp = s;                                                                     \
    EMIT                                                                        \
  }

// ---------------- K345: fused layer-2 spike + fc2 + layer-3 spike, one block per b ----
// The psp (alpha) part of each scan is LINEAR -> computed by a segmented parallel scan
// (16 segs x 32 steps; A^L = d^L [[1,0],[L,1]], d^32 = e^-8) using all 512 threads.
// Only the refractory+threshold feedback stays serial (~9 f64 ops/step, input from LDS).
__global__ __launch_bounds__(512, 1) void k345(const float* __restrict__ w2,
                                               const double* __restrict__ R,
                                               float* __restrict__ out) {
  __shared__ double   p2l[NT * HID];                 // 128 KB; reused as r3l/p3 (NT*NOUT)
  __shared__ double   zcl[16 * HID], ycl[16 * HID];  // segment contributions
  __shared__ double   zil[16 * HID], yil[16 * HID];  // segment incoming states
  __shared__ float    w2l[NOUT * 33];
  __shared__ uint32_t s2l[NT];
  double* r3l = p2l;                                 // phase-C/D/E alias (barriered)

  const int b = blockIdx.x;
  const int tid = threadIdx.x;

  const double dsr = (double)D_SR, ssr = (double)S_SR;
  const double dre = (double)D_REF, cr = (double)C_REF;
  const double K = cr * dre;
  const double DL = 3.3546262790251185e-4;           // e^-8 = d_sr^32

  for (int i = tid; i < NOUT * HID; i += 512) w2l[(i >> 5) * 33 + (i & 31)] = w2[i];

  // ===== phase A: parallel segmented psp scan (layer 2): p2l[t*32+h] = ssr*y_t =====
  {
    const int h = tid & 31;
    const int k = tid >> 5;                          // 0..15
    const int t0 = k * 32;
    const int L = (k == 15) ? (NT - 480) : 32;
    const double* Rb = R + (size_t)b * NT * HID + h;
    double z = 0.0, y = 0.0;
    for (int i = 0; i < L; i++) {                    // zero-init local scan -> contribution
      double x = Rb[(size_t)(t0 + i) * HID];
      y = dsr * (y + z);
      z = __builtin_fma(dsr, z, x);
    }
    zcl[k * HID + h] = z; ycl[k * HID + h] = y;
  }
  __syncthreads();
  if (tid < HID) {                                   // combine across segments (per h)
    const int h = tid;
    double z = 0.0, y = 0.0;
    for (int k = 0; k < 16; k++) {
      zil[k * HID + h] = z; yil[k * HID + h] = y;
      double zc = zcl[k * HID + h], yc = ycl[k * HID + h];
      y = __builtin_fma(DL, __builtin_fma(32.0, z, y), yc);  // y' = d^L(Lz+y)+yc
      z = __builtin_fma(DL, z, zc);                          // z' = d^L z + zc
    }
  }
  __syncthreads();
  {
    const int h = tid & 31;
    const int k = tid >> 5;
    const int t0 = k * 32;
    const int L = (k == 15) ? (NT - 480) : 32;
    const double* Rb = R + (size_t)b * NT * HID + h;
    double z = zil[k * HID + h], y = yil[k * HID + h];
    for (int i = 0; i < L; i++) {                    // re-run with incoming state, emit p
      double x = Rb[(size_t)(t0 + i) * HID];
      y = dsr * (y + z);
      z = __builtin_fma(dsr, z, x);
      p2l[(t0 + i) * HID + h] = ssr * y;
    }
  }
  __syncthreads();

  // ===== phase B: serial refractory (layer 2), lanes 0..31 of wave 0 =====
  if (tid < 32) {
    const int h = tid;
    double q = 0.0, zrd = 0.0;
    bool sp = false;
    double c0 = p2l[0 * HID + h], c1 = p2l[1 * HID + h];
    double c2 = p2l[2 * HID + h], c3 = p2l[3 * HID + h];
#pragma unroll 1
    for (int g = 0; g < 125; g++) {
      const int gp = (g < 124) ? g + 1 : 124;        // clamp; last reload unused
      double n0 = p2l[(gp * 4 + 0) * HID + h];
      double n1 = p2l[(gp * 4 + 1) * HID + h];
      double n2 = p2l[(gp * 4 + 2) * HID + h];
      double n3 = p2l[(gp * 4 + 3) * HID + h];
      const int t = g * 4;
      REF_STEP(c0, { uint32_t mm = (uint32_t)__ballot(s); if (h == 0) s2l[t] = mm; })
      REF_STEP(c1, { uint32_t mm = (uint32_t)__ballot(s); if (h == 0) s2l[t + 1] = mm; })
      REF_STEP(c2, { uint32_t mm = (uint32_t)__ballot(s); if (h == 0) s2l[t + 2] = mm; })
      REF_STEP(c3, { uint32_t mm = (uint32_t)__ballot(s); if (h == 0) s2l[t + 3] = mm; })
      c0 = n0; c1 = n1; c2 = n2; c3 = n3;
    }
  }
  __syncthreads();

  // ===== phase C: fc2 into r3l[t][o] (same gather order as verified k4) =====
#pragma unroll 1
  for (int base = 0; base < NT * NOUT; base += 512) {
    int task = base + tid;
    if (task < NT * NOUT) {
      int o = task % NOUT;
      int t = task / NOUT;
      uint32_t m = s2l[t];
      const float* wr = w2l + o * 33;
      double acc = 0.0;
      while (m) {
        uint32_t i0 = __builtin_ctz(m);                 uint32_t m1_ = m & (m - 1);
        uint32_t i1 = m1_ ? __builtin_ctz(m1_) : 0u;    uint32_t m2_ = m1_ ? (m1_ & (m1_ - 1)) : 0u;
        uint32_t i2 = m2_ ? __builtin_ctz(m2_) : 0u;    uint32_t m3_ = m2_ ? (m2_ & (m2_ - 1)) : 0u;
        uint32_t i3 = m3_ ? __builtin_ctz(m3_) : 0u;    m = m3_ ? (m3_ & (m3_ - 1)) : 0u;
        float a0 = wr[i0];
        float a1 = m1_ ? wr[i1] : 0.0f;
        float a2 = m2_ ? wr[i2] : 0.0f;
        float a3 = m3_ ? wr[i3] : 0.0f;
        acc += (double)a0;
        acc += (double)a1;
        acc += (double)a2;
        acc += (double)a3;
      }
      r3l[t * NOUT + o] = acc;
    }
  }
  __syncthreads();

  // ===== phase D: parallel segmented psp scan (layer 3), in place over r3l =====
  if (tid < 16 * NOUT) {
    const int o = tid % NOUT;
    const int k = tid / NOUT;                        // 0..15
    const int t0 = k * 32;
    const int L = (k == 15) ? (NT - 480) : 32;
    double z = 0.0, y = 0.0;
    for (int i = 0; i < L; i++) {
      double x = r3l[(t0 + i) * NOUT + o];
      y = dsr * (y + z);
      z = __builtin_fma(dsr, z, x);
    }
    zcl[k * NOUT + o] = z; ycl[k * NOUT + o] = y;
  }
  __syncthreads();
  if (tid < NOUT) {
    const int o = tid;
    double z = 0.0, y = 0.0;
    for (int k = 0; k < 16; k++) {
      zil[k * NOUT + o] = z; yil[k * NOUT + o] = y;
      double zc = zcl[k * NOUT + o], yc = ycl[k * NOUT + o];
      y = __builtin_fma(DL, __builtin_fma(32.0, z, y), yc);
      z = __builtin_fma(DL, z, zc);
    }
  }
  __syncthreads();
  if (tid < 16 * NOUT) {
    const int o = tid % NOUT;
    const int k = tid / NOUT;
    const int t0 = k * 32;
    const int L = (k == 15) ? (NT - 480) : 32;
    double z = zil[k * NOUT + o], y = yil[k * NOUT + o];
    for (int i = 0; i < L; i++) {
      const int idx = (t0 + i) * NOUT + o;
      double x = r3l[idx];                           // read-then-overwrite, slot owned
      y = dsr * (y + z);
      z = __builtin_fma(dsr, z, x);
      r3l[idx] = ssr * y;
    }
  }
  __syncthreads();

  // ===== phase E: serial refractory (layer 3), lanes 0..19 -> output =====
  if (tid < NOUT) {
    const int o = tid;
    float* orow = out + ((size_t)b * NOUT + o) * NT;
    double q = 0.0, zrd = 0.0;
    bool sp = false;
    double c0 = r3l[0 * NOUT + o], c1 = r3l[1 * NOUT + o];
    double c2 = r3l[2 * NOUT + o], c3 = r3l[3 * NOUT + o];
#pragma unroll 1
    for (int g = 0; g < 125; g++) {
      const int gp = (g < 124) ? g + 1 : 124;
      double n0 = r3l[(gp * 4 + 0) * NOUT + o];
      double n1 = r3l[(gp * 4 + 1) * NOUT + o];
      double n2 = r3l[(gp * 4 + 2) * NOUT + o];
      double n3 = r3l[(gp * 4 + 3) * NOUT + o];
      float4 ov;
      REF_STEP(c0, { ov.x = s ? 1.0f : 0.0f; })
      REF_STEP(c1, { ov.y = s ? 1.0f : 0.0f; })
      REF_STEP(c2, { ov.z = s ? 1.0f : 0.0f; })
      REF_STEP(c3, { ov.w = s ? 1.0f : 0.0f; })
      *(float4*)(orow + g * 4) = ov;
      c0 = n0; c1 = n1; c2 = n2; c3 = n3;
    }
  }
}

extern "C" void kernel_launch(void* const* d_in, const int* in_sizes, int n_in,
                              void* d_out, int out_size, void* d_ws, size_t ws_size,
                              hipStream_t stream) {
  const float* x  = (const float*)d_in[0];   // [8,6300,500]
  const float* w1 = (const float*)d_in[1];   // [32,6300]
  const float* w2 = (const float*)d_in[2];   // [20,32]
  float* out = (float*)d_out;                // [8,20,500]

  uint8_t* ws = (uint8_t*)d_ws;
  const size_t W1T_BYTES  = (size_t)F_IN * HID * 4;        //   806,400
  const size_t XBF_BYTES  = (size_t)NB * F_IN * NWD * 8;   // 3,225,600
  const size_t MASK_BYTES = (size_t)NB * NW * NT * 8;      // 3,168,000
  float*    w1t   = (float*)ws;
  uint64_t* xbF   = (uint64_t*)(ws + W1T_BYTES);
  uint64_t* masks = (uint64_t*)(ws + W1T_BYTES + XBF_BYTES);
  double*   R     = (double*)(ws + W1T_BYTES + XBF_BYTES + MASK_BYTES);

  k0_pack<<<NROWB + 99, 256, 0, stream>>>(x, w1, xbF, w1t);
  k1_layer1<<<dim3(NW, NB), 64, 0, stream>>>(xbF, masks);
  k2_fc1<<<dim3(NB, NT / 4), 512, 0, stream>>>(w1t, masks, R);
  k345<<<NB, 512, 0, stream>>>(w2, R, out);
}

// Round 7
// 300.994 us; speedup vs baseline: 1.0511x; 1.0511x over previous
//
#include <hip/hip_runtime.h>
#include <stdint.h>

#define NB 8
#define F_IN 6300
#define NT 500
#define HID 32
#define NOUT 20
#define NW 99   // u64 mask words per (b,t) row: ceil(6300/64)
#define NWD 8   // u64 words per (b,f) packed time row: ceil(500/64)

// float32 constants, rounded exactly as np.float32 would round the doubles
#define D_SR   0.7788007830714049f     // exp(-1/4)
#define S_SR   0.6795704571147613f     // e/4
#define D_REF  0.36787944117144233f    // exp(-1)
#define C_REF  -5.43656365691809f      // -2*e

#define NROWB ((NB * F_IN) / 4)        // 12600 pack blocks (4 rows each)

// ---------------- K0: pack x into time-bitmasks (binary input!) + transpose w1 ----------------
__global__ __launch_bounds__(256) void k0_pack(const float* __restrict__ x,
                                               const float* __restrict__ w1,
                                               uint64_t* __restrict__ xb,
                                               float* __restrict__ w1t) {
  const int bid = blockIdx.x;
  const int tid = threadIdx.x;
  if (bid < NROWB) {
    const int row = bid * 4 + (tid >> 6);      // row = b*F_IN + f
    const int lane = tid & 63;
    const float* xr = x + (size_t)row * NT;
    uint64_t m[8];
#pragma unroll
    for (int k = 0; k < 8; k++) {
      int t = k * 64 + lane;
      float v = (t < NT) ? xr[t] : 0.f;
      m[k] = __ballot(v > 0.5f);
    }
    if (lane == 0) {
      uint64_t* dst = xb + (size_t)row * NWD;
#pragma unroll
      for (int k = 0; k < 8; k++) dst[k] = m[k];
    }
    return;
  }
  // ---- transpose w1 [32][6300] -> w1t [6300][32] ----
  __shared__ float tl[64][33];
  const int f0 = (bid - NROWB) * 64;
  const int r = tid & 63, g = tid >> 6;
#pragma unroll
  for (int oo = 0; oo < 32; oo += 4) {
    int o = oo + g;
    int f = f0 + r;
    tl[r][o] = (f < F_IN) ? w1[o * F_IN + f] : 0.f;
  }
  __syncthreads();
#pragma unroll
  for (int k = 0; k < 8; k++) {
    int idx = k * 256 + tid;
    int rr = idx >> 5, cc = idx & 31;
    int f = f0 + rr;
    if (f < F_IN) w1t[(size_t)f * 32 + cc] = tl[rr][cc];
  }
}

// ---------------- K1: layer 1 (psp -> spike) from packed bits, exact-order f32 ----------------
__global__ __launch_bounds__(64, 1) void k1_layer1(const uint64_t* __restrict__ xb,
                                                   uint64_t* __restrict__ masks) {
  const int wi = blockIdx.x;
  const int b  = blockIdx.y;
  const int lane = threadIdx.x;
  const int f = wi * 64 + lane;
  const uint64_t vmask = __ballot(f < F_IN);
  const int fc = (f < F_IN) ? f : (F_IN - 1);
  const uint64_t* xr = xb + ((size_t)b * F_IN + fc) * NWD;
  uint64_t* mrow = masks + ((size_t)b * NW + wi) * NT;

  float y1 = 0.f, z1 = 0.f, yr = 0.f, zr = 0.f;
  uint64_t wcur = xr[0];

#pragma unroll 1
  for (int gg = 0; gg < 8; gg++) {
    const int gn = (gg < 7) ? gg + 1 : 7;
    uint64_t wnxt = xr[gn];
    const uint32_t wlo = (uint32_t)wcur;
    const uint32_t whi = (uint32_t)(wcur >> 32);
    uint64_t keep = 0;
#pragma unroll
    for (int j = 0; j < 64; j++) {
      const uint32_t bw = (j < 32) ? wlo : whi;
      const bool xbit = ((bw >> (j & 31)) & 1u) != 0u;
      float zm = __fmul_rn(D_SR, z1);
      y1 = __fmul_rn(D_SR, __fadd_rn(y1, z1));
      z1 = xbit ? __fadd_rn(zm, 1.0f) : zm;
      float p = __fmul_rn(S_SR, y1);
      yr = __fmul_rn(D_REF, __fadd_rn(yr, zr));
      float u = __fadd_rn(p, __fmul_rn(C_REF, yr));
      bool s = (u >= 1.0f);
      float zrm = __fmul_rn(D_REF, zr);
      zr = s ? __fadd_rn(zrm, 1.0f) : zrm;
      uint64_t mball = __ballot(s);
      if (lane == j) keep = mball;
    }
    uint64_t* mp = mrow + gg * 64;
    if (gg < 7)                 mp[lane] = keep & vmask;
    else if (lane < NT - 7*64)  mp[lane] = keep & vmask;
    wcur = wnxt;
  }
}

// ---------------- K2: sparse fc1: R[b,t,o] = sum_{f active} w1t[f][o] (f64) ----------------
__global__ __launch_bounds__(512) void k2_fc1(const float* __restrict__ w1t,
                                              const uint64_t* __restrict__ masks,
                                              double* __restrict__ R) {
  __shared__ double part[8][32];
  const int tid = threadIdx.x;
  const int wv = tid >> 6;
  const int lane = tid & 63;
  const int half = lane >> 5;
  const int o = lane & 31;
  const int b = blockIdx.x;
  const int t = blockIdx.y * 4 + (wv & 3);
  const int seg = wv >> 2;
  const int wbeg = seg * 50, wend = seg ? NW : 50;
  const uint64_t* mbase = masks + (size_t)b * NW * NT + t;
  const char* wrow = (const char*)w1t + o * 4;
  double acc0 = 0.0, acc1 = 0.0, acc2 = 0.0, acc3 = 0.0;

  int wi = wbeg + half;
  uint64_t mcur = (wi < wend) ? mbase[(size_t)wi * NT] : 0;
  for (; wi < wend; wi += 2) {
    uint64_t mnext = (wi + 2 < wend) ? mbase[(size_t)(wi + 2) * NT] : 0;
    const uint32_t base0 = ((uint32_t)wi << 13);
    uint32_t w = (uint32_t)mcur;
    uint32_t boff = base0;
#pragma unroll
    for (int sub = 0; sub < 2; sub++) {
      while (w) {
        uint32_t i0 = __builtin_ctz(w);                 uint32_t w1_ = w & (w - 1);
        uint32_t i1 = w1_ ? __builtin_ctz(w1_) : 0u;    uint32_t w2_ = w1_ ? (w1_ & (w1_ - 1)) : 0u;
        uint32_t i2 = w2_ ? __builtin_ctz(w2_) : 0u;    uint32_t w3_ = w2_ ? (w2_ & (w2_ - 1)) : 0u;
        uint32_t i3 = w3_ ? __builtin_ctz(w3_) : 0u;    w = w3_ ? (w3_ & (w3_ - 1)) : 0u;
        float a0 = *(const float*)(wrow + boff + (i0 << 7));
        float a1 = *(const float*)(wrow + boff + (i1 << 7));
        float a2 = *(const float*)(wrow + boff + (i2 << 7));
        float a3 = *(const float*)(wrow + boff + (i3 << 7));
        a1 = w1_ ? a1 : 0.0f;
        a2 = w2_ ? a2 : 0.0f;
        a3 = w3_ ? a3 : 0.0f;
        acc0 += (double)a0;
        acc1 += (double)a1;
        acc2 += (double)a2;
        acc3 += (double)a3;
      }
      w = (uint32_t)(mcur >> 32);
      boff = base0 + (32u << 7);
    }
    mcur = mnext;
  }
  double acc = (acc0 + acc1) + (acc2 + acc3);
  int hi2 = __shfl_xor(__double2hiint(acc), 32);
  int lo2 = __shfl_xor(__double2loint(acc), 32);
  acc += __hiloint2double(hi2, lo2);
  if (half == 0) part[wv][o] = acc;
  __syncthreads();
  if (wv < 4 && half == 0) {
    double tot = part[wv][o] + part[wv + 4][o];
    R[((size_t)b * NT + t) * HID + o] = tot;   // [b][t][o]: coalesced 256-B store
  }
}

// ---- minimal-chain exact refractory step: V = C*y, X = C*d*z (u = V + p) ----
// Per step: u=add; cmp; X = sel(d*X, d*X+K); V = fma(d,V,X).
// Chain = cmp -> cndmask -> fma -> add (~4 dependent ops vs 7 in the old form).
// Recurrence is algebraically identical to the reference (X==C*d*z, V==C*y);
// rounding differs ~1ulp/step (same accepted class as the psp-scan reassociation).
#define REF_FAST(pin, EMIT)                                                     \
  {                                                                             \
    double u = V + (pin);                                                       \
    bool s = (u >= 1.0);                                                        \
    double X0 = dre * X;                                                        \
    X = s ? (X0 + K) : X0;                                                      \
    V = __builtin_fma(dre, V, X);                                               \
    EMIT                                                                        \
  }

#define B_GROUP(t, r0, r1, r2, r3)                                              \
  {                                                                             \
    REF_FAST(r0, { uint32_t mm = (uint32_t)__ballot(s); if (h == 0) s2l[(t)] = mm; })     \
    REF_FAST(r1, { uint32_t mm = (uint32_t)__ballot(s); if (h == 0) s2l[(t) + 1] = mm; }) \
    REF_FAST(r2, { uint32_t mm = (uint32_t)__ballot(s); if (h == 0) s2l[(t) + 2] = mm; }) \
    REF_FAST(r3, { uint32_t mm = (uint32_t)__ballot(s); if (h == 0) s2l[(t) + 3] = mm; }) \
  }

#define E_GROUP(t, r0, r1, r2, r3)                                              \
  {                                                                             \
    float4 ov;                                                                  \
    REF_FAST(r0, { ov.x = s ? 1.0f : 0.0f; })                                   \
    REF_FAST(r1, { ov.y = s ? 1.0f : 0.0f; })                                   \
    REF_FAST(r2, { ov.z = s ? 1.0f : 0.0f; })                                   \
    REF_FAST(r3, { ov.w = s ? 1.0f : 0.0f; })                                   \
    *(float4*)(orow + (t)) = ov;                                                \
  }

// ---------------- K345: fused layer-2 spike + fc2 + layer-3 spike, one block per b ----
// psp scans parallel (segmented linear scan, passed R5); refractory scans FULL-LENGTH
// EXACT serial (halo approach was wrong: spike-decision errors don't decay), but with
// the 4-op minimal chain and a 2-group-deep static LDS prefetch ring.
__global__ __launch_bounds__(512, 1) void k345(const float* __restrict__ w2,
                                               const double* __restrict__ R,
                                               float* __restrict__ out) {
  __shared__ double   p2l[NT * HID];                 // 128 KB; reused as r3l/p3 (NT*NOUT)
  __shared__ double   zcl[16 * HID], ycl[16 * HID];  // segment contributions
  __shared__ double   zil[16 * HID], yil[16 * HID];  // segment incoming states
  __shared__ float    w2l[NOUT * 33];
  __shared__ uint32_t s2l[NT];
  double* r3l = p2l;                                 // phase-C/D/E alias (barriered)

  const int b = blockIdx.x;
  const int tid = threadIdx.x;

  const double dsr = (double)D_SR, ssr = (double)S_SR;
  const double dre = (double)D_REF, cr = (double)C_REF;
  const double K = cr * dre;
  const double DL = 3.3546262790251185e-4;           // e^-8 = d_sr^32

  for (int i = tid; i < NOUT * HID; i += 512) w2l[(i >> 5) * 33 + (i & 31)] = w2[i];

  // ===== phase A: parallel segmented psp scan (layer 2): p2l[t*32+h] = ssr*y_t =====
  {
    const int h = tid & 31;
    const int k = tid >> 5;                          // 0..15
    const int t0 = k * 32;
    const int L = (k == 15) ? (NT - 480) : 32;
    const double* Rb = R + (size_t)b * NT * HID + h;
    double z = 0.0, y = 0.0;
    for (int i = 0; i < L; i++) {                    // zero-init local scan -> contribution
      double x = Rb[(size_t)(t0 + i) * HID];
      y = dsr * (y + z);
      z = __builtin_fma(dsr, z, x);
    }
    zcl[k * HID + h] = z; ycl[k * HID + h] = y;
  }
  __syncthreads();
  if (tid < HID) {                                   // combine across segments (per h)
    const int h = tid;
    double z = 0.0, y = 0.0;
    for (int k = 0; k < 16; k++) {
      zil[k * HID + h] = z; yil[k * HID + h] = y;
      double zc = zcl[k * HID + h], yc = ycl[k * HID + h];
      y = __builtin_fma(DL, __builtin_fma(32.0, z, y), yc);  // y' = d^L(Lz+y)+yc
      z = __builtin_fma(DL, z, zc);                          // z' = d^L z + zc
    }
  }
  __syncthreads();
  {
    const int h = tid & 31;
    const int k = tid >> 5;
    const int t0 = k * 32;
    const int L = (k == 15) ? (NT - 480) : 32;
    const double* Rb = R + (size_t)b * NT * HID + h;
    double z = zil[k * HID + h], y = yil[k * HID + h];
    for (int i = 0; i < L; i++) {                    // re-run with incoming state, emit p
      double x = Rb[(size_t)(t0 + i) * HID];
      y = dsr * (y + z);
      z = __builtin_fma(dsr, z, x);
      p2l[(t0 + i) * HID + h] = ssr * y;
    }
  }
  __syncthreads();

  // ===== phase B: EXACT serial refractory (layer 2), 4-op chain, lanes 0..31 =====
  if (tid < 32) {
    const int h = tid;
    double X = 0.0, V = 0.0;
    double a0 = p2l[0 * HID + h], a1 = p2l[1 * HID + h],
           a2 = p2l[2 * HID + h], a3 = p2l[3 * HID + h];          // group 0
    double b0 = p2l[4 * HID + h], b1 = p2l[5 * HID + h],
           b2 = p2l[6 * HID + h], b3 = p2l[7 * HID + h];          // group 1
#pragma unroll 1
    for (int gg = 0; gg < 62; gg++) {
      const int ge = gg * 2;                         // even group 0..122
      {
        const int gp = ge + 2;                       // prefetch even slot (<=124)
        double n0 = p2l[(gp * 4 + 0) * HID + h], n1 = p2l[(gp * 4 + 1) * HID + h],
               n2 = p2l[(gp * 4 + 2) * HID + h], n3 = p2l[(gp * 4 + 3) * HID + h];
        B_GROUP(ge * 4, a0, a1, a2, a3)
        a0 = n0; a1 = n1; a2 = n2; a3 = n3;
      }
      {
        int gp = ge + 3;                             // prefetch odd slot
        if (gp > 124) gp = 124;                      // clamped: value unused in tail
        double n0 = p2l[(gp * 4 + 0) * HID + h], n1 = p2l[(gp * 4 + 1) * HID + h],
               n2 = p2l[(gp * 4 + 2) * HID + h], n3 = p2l[(gp * 4 + 3) * HID + h];
        B_GROUP((ge + 1) * 4, b0, b1, b2, b3)
        b0 = n0; b1 = n1; b2 = n2; b3 = n3;
      }
    }
    B_GROUP(496, a0, a1, a2, a3)                     // tail group 124 (in even slot)
  }
  __syncthreads();

  // ===== phase C: fc2 into r3l[t][o] (same gather order as verified k4) =====
#pragma unroll 1
  for (int base = 0; base < NT * NOUT; base += 512) {
    int task = base + tid;
    if (task < NT * NOUT) {
      int o = task % NOUT;
      int t = task / NOUT;
      uint32_t m = s2l[t];
      const float* wr = w2l + o * 33;
      double acc = 0.0;
      while (m) {
        uint32_t i0 = __builtin_ctz(m);                 uint32_t m1_ = m & (m - 1);
        uint32_t i1 = m1_ ? __builtin_ctz(m1_) : 0u;    uint32_t m2_ = m1_ ? (m1_ & (m1_ - 1)) : 0u;
        uint32_t i2 = m2_ ? __builtin_ctz(m2_) : 0u;    uint32_t m3_ = m2_ ? (m2_ & (m2_ - 1)) : 0u;
        uint32_t i3 = m3_ ? __builtin_ctz(m3_) : 0u;    m = m3_ ? (m3_ & (m3_ - 1)) : 0u;
        float a0 = wr[i0];
        float a1 = m1_ ? wr[i1] : 0.0f;
        float a2 = m2_ ? wr[i2] : 0.0f;
        float a3 = m3_ ? wr[i3] : 0.0f;
        acc += (double)a0;
        acc += (double)a1;
        acc += (double)a2;
        acc += (double)a3;
      }
      r3l[t * NOUT + o] = acc;
    }
  }
  __syncthreads();

  // ===== phase D: parallel segmented psp scan (layer 3), in place over r3l =====
  if (tid < 16 * NOUT) {
    const int o = tid % NOUT;
    const int k = tid / NOUT;                        // 0..15
    const int t0 = k * 32;
    const int L = (k == 15) ? (NT - 480) : 32;
    double z = 0.0, y = 0.0;
    for (int i = 0; i < L; i++) {
      double x = r3l[(t0 + i) * NOUT + o];
      y = dsr * (y + z);
      z = __builtin_fma(dsr, z, x);
    }
    zcl[k * NOUT + o] = z; ycl[k * NOUT + o] = y;
  }
  __syncthreads();
  if (tid < NOUT) {
    const int o = tid;
    double z = 0.0, y = 0.0;
    for (int k = 0; k < 16; k++) {
      zil[k * NOUT + o] = z; yil[k * NOUT + o] = y;
      double zc = zcl[k * NOUT + o], yc = ycl[k * NOUT + o];
      y = __builtin_fma(DL, __builtin_fma(32.0, z, y), yc);
      z = __builtin_fma(DL, z, zc);
    }
  }
  __syncthreads();
  if (tid < 16 * NOUT) {
    const int o = tid % NOUT;
    const int k = tid / NOUT;
    const int t0 = k * 32;
    const int L = (k == 15) ? (NT - 480) : 32;
    double z = zil[k * NOUT + o], y = yil[k * NOUT + o];
    for (int i = 0; i < L; i++) {
      const int idx = (t0 + i) * NOUT + o;
      double x = r3l[idx];                           // read-then-overwrite, slot owned
      y = dsr * (y + z);
      z = __builtin_fma(dsr, z, x);
      r3l[idx] = ssr * y;
    }
  }
  __syncthreads();

  // ===== phase E: EXACT serial refractory (layer 3), 4-op chain, lanes 0..19 =====
  if (tid < NOUT) {
    const int o = tid;
    float* orow = out + ((size_t)b * NOUT + o) * NT;
    double X = 0.0, V = 0.0;
    double a0 = r3l[0 * NOUT + o], a1 = r3l[1 * NOUT + o],
           a2 = r3l[2 * NOUT + o], a3 = r3l[3 * NOUT + o];        // group 0
    double b0 = r3l[4 * NOUT + o], b1 = r3l[5 * NOUT + o],
           b2 = r3l[6 * NOUT + o], b3 = r3l[7 * NOUT + o];        // group 1
#pragma unroll 1
    for (int gg = 0; gg < 62; gg++) {
      const int ge = gg * 2;
      {
        const int gp = ge + 2;
        double n0 = r3l[(gp * 4 + 0) * NOUT + o], n1 = r3l[(gp * 4 + 1) * NOUT + o],
               n2 = r3l[(gp * 4 + 2) * NOUT + o], n3 = r3l[(gp * 4 + 3) * NOUT + o];
        E_GROUP(ge * 4, a0, a1, a2, a3)
        a0 = n0; a1 = n1; a2 = n2; a3 = n3;
      }
      {
        int gp = ge + 3;
        if (gp > 124) gp = 124;                      // clamped: value unused in tail
        double n0 = r3l[(gp * 4 + 0) * NOUT + o], n1 = r3l[(gp * 4 + 1) * NOUT + o],
               n2 = r3l[(gp * 4 + 2) * NOUT + o], n3 = r3l[(gp * 4 + 3) * NOUT + o];
        E_GROUP((ge + 1) * 4, b0, b1, b2, b3)
        b0 = n0; b1 = n1; b2 = n2; b3 = n3;
      }
    }
    E_GROUP(496, a0, a1, a2, a3)                     // tail group 124
  }
}

extern "C" void kernel_launch(void* const* d_in, const int* in_sizes, int n_in,
                              void* d_out, int out_size, void* d_ws, size_t ws_size,
                              hipStream_t stream) {
  const float* x  = (const float*)d_in[0];   // [8,6300,500]
  const float* w1 = (const float*)d_in[1];   // [32,6300]
  const float* w2 = (const float*)d_in[2];   // [20,32]
  float* out = (float*)d_out;                // [8,20,500]

  uint8_t* ws = (uint8_t*)d_ws;
  const size_t W1T_BYTES  = (size_t)F_IN * HID * 4;        //   806,400
  const size_t XBF_BYTES  = (size_t)NB * F_IN * NWD * 8;   // 3,225,600
  const size_t MASK_BYTES = (size_t)NB * NW * NT * 8;      // 3,168,000
  float*    w1t   = (float*)ws;
  uint64_t* xbF   = (uint64_t*)(ws + W1T_BYTES);
  uint64_t* masks = (uint64_t*)(ws + W1T_BYTES + XBF_BYTES);
  double*   R     = (double*)(ws + W1T_BYTES + XBF_BYTES + MASK_BYTES);

  k0_pack<<<NROWB + 99, 256, 0, stream>>>(x, w1, xbF, w1t);
  k1_layer1<<<dim3(NW, NB), 64, 0, stream>>>(xbF, masks);
  k2_fc1<<<dim3(NB, NT / 4), 512, 0, stream>>>(w1t, masks, R);
  k345<<<NB, 512, 0, stream>>>(w2, R, out);
}

// Round 8
// 297.702 us; speedup vs baseline: 1.0627x; 1.0111x over previous
//
#include <hip/hip_runtime.h>
#include <stdint.h>

#define NB 8
#define F_IN 6300
#define NT 500
#define HID 32
#define NOUT 20
#define NW 99   // u64 mask words per (b,t) row: ceil(6300/64)
#define NWD 8   // u64 words per (b,f) packed time row: ceil(500/64)

// float32 constants, rounded exactly as np.float32 would round the doubles
#define D_SR   0.7788007830714049f     // exp(-1/4)
#define S_SR   0.6795704571147613f     // e/4
#define D_REF  0.36787944117144233f    // exp(-1)
#define C_REF  -5.43656365691809f      // -2*e

#define NROWB ((NB * F_IN) / 4)        // 12600 pack blocks (4 rows each)

// ---------------- K0: pack x into time-bitmasks (binary input!) + transpose w1 ----------------
__global__ __launch_bounds__(256) void k0_pack(const float* __restrict__ x,
                                               const float* __restrict__ w1,
                                               uint64_t* __restrict__ xb,
                                               float* __restrict__ w1t) {
  const int bid = blockIdx.x;
  const int tid = threadIdx.x;
  if (bid < NROWB) {
    const int row = bid * 4 + (tid >> 6);      // row = b*F_IN + f
    const int lane = tid & 63;
    const float* xr = x + (size_t)row * NT;
    uint64_t m[8];
#pragma unroll
    for (int k = 0; k < 8; k++) {
      int t = k * 64 + lane;
      float v = (t < NT) ? xr[t] : 0.f;
      m[k] = __ballot(v > 0.5f);
    }
    if (lane == 0) {
      uint64_t* dst = xb + (size_t)row * NWD;
#pragma unroll
      for (int k = 0; k < 8; k++) dst[k] = m[k];
    }
    return;
  }
  // ---- transpose w1 [32][6300] -> w1t [6300][32] ----
  __shared__ float tl[64][33];
  const int f0 = (bid - NROWB) * 64;
  const int r = tid & 63, g = tid >> 6;
#pragma unroll
  for (int oo = 0; oo < 32; oo += 4) {
    int o = oo + g;
    int f = f0 + r;
    tl[r][o] = (f < F_IN) ? w1[o * F_IN + f] : 0.f;
  }
  __syncthreads();
#pragma unroll
  for (int k = 0; k < 8; k++) {
    int idx = k * 256 + tid;
    int rr = idx >> 5, cc = idx & 31;
    int f = f0 + rr;
    if (f < F_IN) w1t[(size_t)f * 32 + cc] = tl[rr][cc];
  }
}

// ---------------- K1: layer 1 (psp -> spike) from packed bits, exact-order f32 ----------------
__global__ __launch_bounds__(64, 1) void k1_layer1(const uint64_t* __restrict__ xb,
                                                   uint64_t* __restrict__ masks) {
  const int wi = blockIdx.x;
  const int b  = blockIdx.y;
  const int lane = threadIdx.x;
  const int f = wi * 64 + lane;
  const uint64_t vmask = __ballot(f < F_IN);
  const int fc = (f < F_IN) ? f : (F_IN - 1);
  const uint64_t* xr = xb + ((size_t)b * F_IN + fc) * NWD;
  uint64_t* mrow = masks + ((size_t)b * NW + wi) * NT;

  float y1 = 0.f, z1 = 0.f, yr = 0.f, zr = 0.f;
  uint64_t wcur = xr[0];

#pragma unroll 1
  for (int gg = 0; gg < 8; gg++) {
    const int gn = (gg < 7) ? gg + 1 : 7;
    uint64_t wnxt = xr[gn];
    const uint32_t wlo = (uint32_t)wcur;
    const uint32_t whi = (uint32_t)(wcur >> 32);
    uint64_t keep = 0;
#pragma unroll
    for (int j = 0; j < 64; j++) {
      const uint32_t bw = (j < 32) ? wlo : whi;
      const bool xbit = ((bw >> (j & 31)) & 1u) != 0u;
      float zm = __fmul_rn(D_SR, z1);
      y1 = __fmul_rn(D_SR, __fadd_rn(y1, z1));
      z1 = xbit ? __fadd_rn(zm, 1.0f) : zm;
      float p = __fmul_rn(S_SR, y1);
      yr = __fmul_rn(D_REF, __fadd_rn(yr, zr));
      float u = __fadd_rn(p, __fmul_rn(C_REF, yr));
      bool s = (u >= 1.0f);
      float zrm = __fmul_rn(D_REF, zr);
      zr = s ? __fadd_rn(zrm, 1.0f) : zrm;
      uint64_t mball = __ballot(s);
      if (lane == j) keep = mball;
    }
    uint64_t* mp = mrow + gg * 64;
    if (gg < 7)                 mp[lane] = keep & vmask;
    else if (lane < NT - 7*64)  mp[lane] = keep & vmask;
    wcur = wnxt;
  }
}

// ---------------- K2: sparse fc1: R[b,t,o] = sum_{f active} w1t[f][o] (f64) ----------------
__global__ __launch_bounds__(512) void k2_fc1(const float* __restrict__ w1t,
                                              const uint64_t* __restrict__ masks,
                                              double* __restrict__ R) {
  __shared__ double part[8][32];
  const int tid = threadIdx.x;
  const int wv = tid >> 6;
  const int lane = tid & 63;
  const int half = lane >> 5;
  const int o = lane & 31;
  const int b = blockIdx.x;
  const int t = blockIdx.y * 4 + (wv & 3);
  const int seg = wv >> 2;
  const int wbeg = seg * 50, wend = seg ? NW : 50;
  const uint64_t* mbase = masks + (size_t)b * NW * NT + t;
  const char* wrow = (const char*)w1t + o * 4;
  double acc0 = 0.0, acc1 = 0.0, acc2 = 0.0, acc3 = 0.0;

  int wi = wbeg + half;
  uint64_t mcur = (wi < wend) ? mbase[(size_t)wi * NT] : 0;
  for (; wi < wend; wi += 2) {
    uint64_t mnext = (wi + 2 < wend) ? mbase[(size_t)(wi + 2) * NT] : 0;
    const uint32_t base0 = ((uint32_t)wi << 13);
    uint32_t w = (uint32_t)mcur;
    uint32_t boff = base0;
#pragma unroll
    for (int sub = 0; sub < 2; sub++) {
      while (w) {
        uint32_t i0 = __builtin_ctz(w);                 uint32_t w1_ = w & (w - 1);
        uint32_t i1 = w1_ ? __builtin_ctz(w1_) : 0u;    uint32_t w2_ = w1_ ? (w1_ & (w1_ - 1)) : 0u;
        uint32_t i2 = w2_ ? __builtin_ctz(w2_) : 0u;    uint32_t w3_ = w2_ ? (w2_ & (w2_ - 1)) : 0u;
        uint32_t i3 = w3_ ? __builtin_ctz(w3_) : 0u;    w = w3_ ? (w3_ & (w3_ - 1)) : 0u;
        float a0 = *(const float*)(wrow + boff + (i0 << 7));
        float a1 = *(const float*)(wrow + boff + (i1 << 7));
        float a2 = *(const float*)(wrow + boff + (i2 << 7));
        float a3 = *(const float*)(wrow + boff + (i3 << 7));
        a1 = w1_ ? a1 : 0.0f;
        a2 = w2_ ? a2 : 0.0f;
        a3 = w3_ ? a3 : 0.0f;
        acc0 += (double)a0;
        acc1 += (double)a1;
        acc2 += (double)a2;
        acc3 += (double)a3;
      }
      w = (uint32_t)(mcur >> 32);
      boff = base0 + (32u << 7);
    }
    mcur = mnext;
  }
  double acc = (acc0 + acc1) + (acc2 + acc3);
  int hi2 = __shfl_xor(__double2hiint(acc), 32);
  int lo2 = __shfl_xor(__double2loint(acc), 32);
  acc += __hiloint2double(hi2, lo2);
  if (half == 0) part[wv][o] = acc;
  __syncthreads();
  if (wv < 4 && half == 0) {
    double tot = part[wv][o] + part[wv + 4][o];
    R[((size_t)b * NT + t) * HID + o] = tot;   // [b][t][o]: coalesced 256-B store
  }
}

// ---- minimal-chain refractory step in F32 (V = C*y, X = C*d*z; u = V + p) ----
// f32 chain ops: ~2-cyc issue, ~4-6 cyc dependent latency (vs f64 4-cyc/~12-15).
// Error vs exact ~3e-7; the f32 REFERENCE itself deviates ~1e-6 from exact yet all
// decisions matched our f64 for 5 rounds -> margins > 1e-6 -> f32 chain is safe.
#define REF_FAST32(pin, EMIT)                                                   \
  {                                                                             \
    float u = V + (pin);                                                        \
    bool s = (u >= 1.0f);                                                       \
    float X0 = dref * X;                                                        \
    X = s ? (X0 + Kf) : X0;                                                     \
    V = __builtin_fmaf(dref, V, X);                                             \
    EMIT                                                                        \
  }

#define B_GROUP(t, r0, r1, r2, r3)                                              \
  {                                                                             \
    REF_FAST32(r0, { uint32_t mm = (uint32_t)__ballot(s); if (h == 0) s2l[(t)] = mm; })     \
    REF_FAST32(r1, { uint32_t mm = (uint32_t)__ballot(s); if (h == 0) s2l[(t) + 1] = mm; }) \
    REF_FAST32(r2, { uint32_t mm = (uint32_t)__ballot(s); if (h == 0) s2l[(t) + 2] = mm; }) \
    REF_FAST32(r3, { uint32_t mm = (uint32_t)__ballot(s); if (h == 0) s2l[(t) + 3] = mm; }) \
  }

#define E_GROUP(t, r0, r1, r2, r3)                                              \
  {                                                                             \
    float4 ov;                                                                  \
    REF_FAST32(r0, { ov.x = s ? 1.0f : 0.0f; })                                 \
    REF_FAST32(r1, { ov.y = s ? 1.0f : 0.0f; })                                 \
    REF_FAST32(r2, { ov.z = s ? 1.0f : 0.0f; })                                 \
    REF_FAST32(r3, { ov.w = s ? 1.0f : 0.0f; })                                 \
    *(float4*)(orow + (t)) = ov;                                                \
  }

// ---------------- K345: fused layer-2 spike + fc2 + layer-3 spike, one block per b ----
// Structure verbatim from the passing R7 kernel; ONLY phases B/E switch their serial
// chain arithmetic to f32 (f64 LDS values converted off-chain in the prefetch).
__global__ __launch_bounds__(512, 1) void k345(const float* __restrict__ w2,
                                               const double* __restrict__ R,
                                               float* __restrict__ out) {
  __shared__ double   p2l[NT * HID];                 // 128 KB; reused as r3l/p3 (NT*NOUT)
  __shared__ double   zcl[16 * HID], ycl[16 * HID];  // segment contributions
  __shared__ double   zil[16 * HID], yil[16 * HID];  // segment incoming states
  __shared__ float    w2l[NOUT * 33];
  __shared__ uint32_t s2l[NT];
  double* r3l = p2l;                                 // phase-C/D/E alias (barriered)

  const int b = blockIdx.x;
  const int tid = threadIdx.x;

  const double dsr = (double)D_SR, ssr = (double)S_SR;
  const double dre = (double)D_REF, cr = (double)C_REF;
  const double K = cr * dre;
  const double DL = 3.3546262790251185e-4;           // e^-8 = d_sr^32

  for (int i = tid; i < NOUT * HID; i += 512) w2l[(i >> 5) * 33 + (i & 31)] = w2[i];

  // ===== phase A: parallel segmented psp scan (layer 2): p2l[t*32+h] = ssr*y_t =====
  {
    const int h = tid & 31;
    const int k = tid >> 5;                          // 0..15
    const int t0 = k * 32;
    const int L = (k == 15) ? (NT - 480) : 32;
    const double* Rb = R + (size_t)b * NT * HID + h;
    double z = 0.0, y = 0.0;
    for (int i = 0; i < L; i++) {                    // zero-init local scan -> contribution
      double x = Rb[(size_t)(t0 + i) * HID];
      y = dsr * (y + z);
      z = __builtin_fma(dsr, z, x);
    }
    zcl[k * HID + h] = z; ycl[k * HID + h] = y;
  }
  __syncthreads();
  if (tid < HID) {                                   // combine across segments (per h)
    const int h = tid;
    double z = 0.0, y = 0.0;
    for (int k = 0; k < 16; k++) {
      zil[k * HID + h] = z; yil[k * HID + h] = y;
      double zc = zcl[k * HID + h], yc = ycl[k * HID + h];
      y = __builtin_fma(DL, __builtin_fma(32.0, z, y), yc);  // y' = d^L(Lz+y)+yc
      z = __builtin_fma(DL, z, zc);                          // z' = d^L z + zc
    }
  }
  __syncthreads();
  {
    const int h = tid & 31;
    const int k = tid >> 5;
    const int t0 = k * 32;
    const int L = (k == 15) ? (NT - 480) : 32;
    const double* Rb = R + (size_t)b * NT * HID + h;
    double z = zil[k * HID + h], y = yil[k * HID + h];
    for (int i = 0; i < L; i++) {                    // re-run with incoming state, emit p
      double x = Rb[(size_t)(t0 + i) * HID];
      y = dsr * (y + z);
      z = __builtin_fma(dsr, z, x);
      p2l[(t0 + i) * HID + h] = ssr * y;
    }
  }
  __syncthreads();

  // ===== phase B: serial refractory (layer 2), F32 4-op chain, lanes 0..31 =====
  if (tid < 32) {
    const int h = tid;
    const float dref = D_REF;
    const float Kf = (float)((double)C_REF * (double)D_REF);   // ~ -2.0f
    float X = 0.f, V = 0.f;
    float a0 = (float)p2l[0 * HID + h], a1 = (float)p2l[1 * HID + h],
          a2 = (float)p2l[2 * HID + h], a3 = (float)p2l[3 * HID + h];   // group 0
    float b0 = (float)p2l[4 * HID + h], b1 = (float)p2l[5 * HID + h],
          b2 = (float)p2l[6 * HID + h], b3 = (float)p2l[7 * HID + h];   // group 1
#pragma unroll 1
    for (int gg = 0; gg < 62; gg++) {
      const int ge = gg * 2;                         // even group 0..122
      {
        const int gp = ge + 2;                       // prefetch even slot (<=124)
        float n0 = (float)p2l[(gp * 4 + 0) * HID + h], n1 = (float)p2l[(gp * 4 + 1) * HID + h],
              n2 = (float)p2l[(gp * 4 + 2) * HID + h], n3 = (float)p2l[(gp * 4 + 3) * HID + h];
        B_GROUP(ge * 4, a0, a1, a2, a3)
        a0 = n0; a1 = n1; a2 = n2; a3 = n3;
      }
      {
        int gp = ge + 3;                             // prefetch odd slot
        if (gp > 124) gp = 124;                      // clamped: value unused in tail
        float n0 = (float)p2l[(gp * 4 + 0) * HID + h], n1 = (float)p2l[(gp * 4 + 1) * HID + h],
              n2 = (float)p2l[(gp * 4 + 2) * HID + h], n3 = (float)p2l[(gp * 4 + 3) * HID + h];
        B_GROUP((ge + 1) * 4, b0, b1, b2, b3)
        b0 = n0; b1 = n1; b2 = n2; b3 = n3;
      }
    }
    B_GROUP(496, a0, a1, a2, a3)                     // tail group 124 (in even slot)
  }
  __syncthreads();

  // ===== phase C: fc2 into r3l[t][o] (same gather order as verified k4) =====
#pragma unroll 1
  for (int base = 0; base < NT * NOUT; base += 512) {
    int task = base + tid;
    if (task < NT * NOUT) {
      int o = task % NOUT;
      int t = task / NOUT;
      uint32_t m = s2l[t];
      const float* wr = w2l + o * 33;
      double acc = 0.0;
      while (m) {
        uint32_t i0 = __builtin_ctz(m);                 uint32_t m1_ = m & (m - 1);
        uint32_t i1 = m1_ ? __builtin_ctz(m1_) : 0u;    uint32_t m2_ = m1_ ? (m1_ & (m1_ - 1)) : 0u;
        uint32_t i2 = m2_ ? __builtin_ctz(m2_) : 0u;    uint32_t m3_ = m2_ ? (m2_ & (m2_ - 1)) : 0u;
        uint32_t i3 = m3_ ? __builtin_ctz(m3_) : 0u;    m = m3_ ? (m3_ & (m3_ - 1)) : 0u;
        float a0 = wr[i0];
        float a1 = m1_ ? wr[i1] : 0.0f;
        float a2 = m2_ ? wr[i2] : 0.0f;
        float a3 = m3_ ? wr[i3] : 0.0f;
        acc += (double)a0;
        acc += (double)a1;
        acc += (double)a2;
        acc += (double)a3;
      }
      r3l[t * NOUT + o] = acc;
    }
  }
  __syncthreads();

  // ===== phase D: parallel segmented psp scan (layer 3), in place over r3l =====
  if (tid < 16 * NOUT) {
    const int o = tid % NOUT;
    const int k = tid / NOUT;                        // 0..15
    const int t0 = k * 32;
    const int L = (k == 15) ? (NT - 480) : 32;
    double z = 0.0, y = 0.0;
    for (int i = 0; i < L; i++) {
      double x = r3l[(t0 + i) * NOUT + o];
      y = dsr * (y + z);
      z = __builtin_fma(dsr, z, x);
    }
    zcl[k * NOUT + o] = z; ycl[k * NOUT + o] = y;
  }
  __syncthreads();
  if (tid < NOUT) {
    const int o = tid;
    double z = 0.0, y = 0.0;
    for (int k = 0; k < 16; k++) {
      zil[k * NOUT + o] = z; yil[k * NOUT + o] = y;
      double zc = zcl[k * NOUT + o], yc = ycl[k * NOUT + o];
      y = __builtin_fma(DL, __builtin_fma(32.0, z, y), yc);
      z = __builtin_fma(DL, z, zc);
    }
  }
  __syncthreads();
  if (tid < 16 * NOUT) {
    const int o = tid % NOUT;
    const int k = tid / NOUT;
    const int t0 = k * 32;
    const int L = (k == 15) ? (NT - 480) : 32;
    double z = zil[k * NOUT + o], y = yil[k * NOUT + o];
    for (int i = 0; i < L; i++) {
      const int idx = (t0 + i) * NOUT + o;
      double x = r3l[idx];                           // read-then-overwrite, slot owned
      y = dsr * (y + z);
      z = __builtin_fma(dsr, z, x);
      r3l[idx] = ssr * y;
    }
  }
  __syncthreads();

  // ===== phase E: serial refractory (layer 3), F32 4-op chain, lanes 0..19 =====
  if (tid < NOUT) {
    const int o = tid;
    float* orow = out + ((size_t)b * NOUT + o) * NT;
    const float dref = D_REF;
    const float Kf = (float)((double)C_REF * (double)D_REF);
    float X = 0.f, V = 0.f;
    float a0 = (float)r3l[0 * NOUT + o], a1 = (float)r3l[1 * NOUT + o],
          a2 = (float)r3l[2 * NOUT + o], a3 = (float)r3l[3 * NOUT + o];  // group 0
    float b0 = (float)r3l[4 * NOUT + o], b1 = (float)r3l[5 * NOUT + o],
          b2 = (float)r3l[6 * NOUT + o], b3 = (float)r3l[7 * NOUT + o];  // group 1
#pragma unroll 1
    for (int gg = 0; gg < 62; gg++) {
      const int ge = gg * 2;
      {
        const int gp = ge + 2;
        float n0 = (float)r3l[(gp * 4 + 0) * NOUT + o], n1 = (float)r3l[(gp * 4 + 1) * NOUT + o],
              n2 = (float)r3l[(gp * 4 + 2) * NOUT + o], n3 = (float)r3l[(gp * 4 + 3) * NOUT + o];
        E_GROUP(ge * 4, a0, a1, a2, a3)
        a0 = n0; a1 = n1; a2 = n2; a3 = n3;
      }
      {
        int gp = ge + 3;
        if (gp > 124) gp = 124;                      // clamped: value unused in tail
        float n0 = (float)r3l[(gp * 4 + 0) * NOUT + o], n1 = (float)r3l[(gp * 4 + 1) * NOUT + o],
              n2 = (float)r3l[(gp * 4 + 2) * NOUT + o], n3 = (float)r3l[(gp * 4 + 3) * NOUT + o];
        E_GROUP((ge + 1) * 4, b0, b1, b2, b3)
        b0 = n0; b1 = n1; b2 = n2; b3 = n3;
      }
    }
    E_GROUP(496, a0, a1, a2, a3)                     // tail group 124
  }
}

extern "C" void kernel_launch(void* const* d_in, const int* in_sizes, int n_in,
                              void* d_out, int out_size, void* d_ws, size_t ws_size,
                              hipStream_t stream) {
  const float* x  = (const float*)d_in[0];   // [8,6300,500]
  const float* w1 = (const float*)d_in[1];   // [32,6300]
  const float* w2 = (const float*)d_in[2];   // [20,32]
  float* out = (float*)d_out;                // [8,20,500]

  uint8_t* ws = (uint8_t*)d_ws;
  const size_t W1T_BYTES  = (size_t)F_IN * HID * 4;        //   806,400
  const size_t XBF_BYTES  = (size_t)NB * F_IN * NWD * 8;   // 3,225,600
  const size_t MASK_BYTES = (size_t)NB * NW * NT * 8;      // 3,168,000
  float*    w1t   = (float*)ws;
  uint64_t* xbF   = (uint64_t*)(ws + W1T_BYTES);
  uint64_t* masks = (uint64_t*)(ws + W1T_BYTES + XBF_BYTES);
  double*   R     = (double*)(ws + W1T_BYTES + XBF_BYTES + MASK_BYTES);

  k0_pack<<<NROWB + 99, 256, 0, stream>>>(x, w1, xbF, w1t);
  k1_layer1<<<dim3(NW, NB), 64, 0, stream>>>(xbF, masks);
  k2_fc1<<<dim3(NB, NT / 4), 512, 0, stream>>>(w1t, masks, R);
  k345<<<NB, 512, 0, stream>>>(w2, R, out);
}